// Round 15
// baseline (277.727 us; speedup 1.0000x reference)
//
#include <hip/hip_runtime.h>

typedef unsigned short u16;
typedef unsigned char u8;
typedef unsigned int u32;
typedef float f32x4 __attribute__((ext_vector_type(4)));
typedef __bf16 bf16x8 __attribute__((ext_vector_type(8)));

#define SPB 6291456      // bytes per packed branch: B*N*C = 16*1024*384 (u8, 4 t-bits)

// ---- async global->LDS, 16B per lane, dest = wave-uniform base + lane*16 ----
__device__ __forceinline__ void gll16(const void* g, void* l) {
  __builtin_amdgcn_global_load_lds((const __attribute__((address_space(1))) void*)g,
                                   (__attribute__((address_space(3))) void*)l, 16, 0, 0);
}

// expand 8 packed spike-bytes (bit t) -> 8 bf16 {0,1}; perm+mul: (b0|b1<<16)*0x3F80
__device__ __forceinline__ uint4 expand8f(uint2 v, u32 t) {
  u32 a = (v.x >> t) & 0x01010101u;
  u32 b = (v.y >> t) & 0x01010101u;
  uint4 r;
  r.x = __builtin_amdgcn_perm(0u, a, 0x0C010C00u) * 0x3F80u;
  r.y = __builtin_amdgcn_perm(0u, a, 0x0C030C02u) * 0x3F80u;
  r.z = __builtin_amdgcn_perm(0u, b, 0x0C010C00u) * 0x3F80u;
  r.w = __builtin_amdgcn_perm(0u, b, 0x0C030C02u) * 0x3F80u;
  return r;
}

// ---------------- K0: weights -> bf16 (stacked q,k,v), BN params fused ----------------
__global__ __launch_bounds__(256) void k_convert(
    const float* __restrict__ qw, const float* __restrict__ kw,
    const float* __restrict__ vw, const float* __restrict__ pw,
    const float* __restrict__ qg, const float* __restrict__ qbt,
    const float* __restrict__ qm, const float* __restrict__ qv,
    const float* __restrict__ kg, const float* __restrict__ kbt,
    const float* __restrict__ km, const float* __restrict__ kv,
    const float* __restrict__ vg, const float* __restrict__ vbt,
    const float* __restrict__ vm, const float* __restrict__ vv,
    const float* __restrict__ pg, const float* __restrict__ pbt,
    const float* __restrict__ pm, const float* __restrict__ pv,
    const float* __restrict__ pbias,
    u16* __restrict__ Wstk, u16* __restrict__ Pw,
    float4* __restrict__ BNP, float4* __restrict__ PP) {
  int tid = blockIdx.x * 256 + threadIdx.x;
  if (tid < 442368) {               // Wstk[1152][384]
    int r = tid / 384, c = tid - r * 384;
    const float* src = (r < 384) ? qw : (r < 768) ? kw : vw;
    int rr = (r >= 768) ? r - 768 : (r >= 384) ? r - 384 : r;
    unsigned int u = __float_as_uint(src[rr * 384 + c]);
    u = (u + 0x7FFFu + ((u >> 16) & 1u)) >> 16;   // RNE to bf16
    Wstk[tid] = (u16)u;
  } else if (tid < 589824) {        // Pw[384][384]
    int i = tid - 442368;
    unsigned int u = __float_as_uint(pw[i]);
    u = (u + 0x7FFFu + ((u >> 16) & 1u)) >> 16;
    Pw[i] = (u16)u;
  } else if (tid < 590976) {        // BNP[1152] = {inv, mean, beta, -}
    int r = tid - 589824;
    int br = r / 384, ch = r - br * 384;
    const float* g  = (br == 0) ? qg  : (br == 1) ? kg  : vg;
    const float* bt = (br == 0) ? qbt : (br == 1) ? kbt : vbt;
    const float* m  = (br == 0) ? qm  : (br == 1) ? km  : vm;
    const float* va = (br == 0) ? qv  : (br == 1) ? kv  : vv;
    float inv = g[ch] / sqrtf(va[ch] + 1e-5f);
    BNP[r] = make_float4(inv, m[ch], bt[ch], 0.f);
  } else if (tid < 591360) {        // PP[384] = {inv, mean, beta, bias}
    int ch = tid - 590976;
    float inv = pg[ch] / sqrtf(pv[ch] + 1e-5f);
    PP[ch] = make_float4(inv, pm[ch], pbt[ch], pbias[ch]);
  }
}

// ---------------- K1: input LIF -> packed nibble xsb[(b*1024+n)*384 + c] --------------
// float4 reads along n (4x fewer load instrs than scalar); phase-2 transpose unchanged.
__global__ __launch_bounds__(256) void k_lif_in(const float* __restrict__ x, u8* __restrict__ xsb) {
  const int nt = blockIdx.x, ct = blockIdx.y, b = blockIdx.z;
  const int tid = threadIdx.x;
  const int n4 = tid & 15, cL = tid >> 4;     // 16 n-quads x 16 c-lanes
  const int c0 = ct * 64, n0 = nt * 64;
  __shared__ u32 nibs[64 * 65];               // [n][c], 65-pad -> 2-way max on writes
  float v[4][4];
  u32 nib[4][4];
  #pragma unroll
  for (int it = 0; it < 4; ++it)
    #pragma unroll
    for (int ns = 0; ns < 4; ++ns) { v[it][ns] = 0.f; nib[it][ns] = 0u; }
  for (int t = 0; t < 4; ++t) {
    #pragma unroll
    for (int it = 0; it < 4; ++it) {
      const float4 xv = *(const float4*)&x[(size_t)(((t * 16 + b) * 384 + c0 + cL + it * 16)) * 1024
                                           + n0 + n4 * 4];
      #pragma unroll
      for (int ns = 0; ns < 4; ++ns) {
        float xe = (ns == 0) ? xv.x : (ns == 1) ? xv.y : (ns == 2) ? xv.z : xv.w;
        float vv = v[it][ns];
        float h = __fadd_rn(vv, __fmul_rn(__fsub_rn(xe, vv), 0.5f));  // v + (x-v)/2, exact order
        bool s = h >= 1.f;
        v[it][ns] = s ? 0.f : h;
        nib[it][ns] |= (s ? 1u : 0u) << t;
      }
    }
  }
  #pragma unroll
  for (int it = 0; it < 4; ++it)
    #pragma unroll
    for (int ns = 0; ns < 4; ++ns)
      nibs[(n4 * 4 + ns) * 65 + cL + it * 16] = nib[it][ns];
  __syncthreads();
  const int n = tid >> 2, ch = tid & 3;
  u32 w0[4];
  #pragma unroll
  for (int q = 0; q < 4; ++q) {
    u32 acc = 0;
    #pragma unroll
    for (int i = 0; i < 4; ++i)
      acc |= (nibs[n * 65 + ch * 16 + q * 4 + i] & 0xFu) << (8 * i);
    w0[q] = acc;
  }
  *(uint4*)(xsb + ((size_t)(b * 1024 + n0 + n)) * 384 + c0 + ch * 16) =
      make_uint4(w0[0], w0[1], w0[2], w0[3]);
}

// ======================================================================================
// GEMM core v10 (ring-3, 3 blocks/CU): BM=128 c, BN=256 j (64 n x 4 t), K=384, 8 waves.
// Wave w owns 8 n-rows (32 j) and ALL 128 c: ji=2, ci=8 -> 16 MFMA/wave/tile, unique-A.
// X packed-resident in LDS (26 KB, 416B-padded rows), expanded to bf16 on read.
// W pipelined: 3 x 8KB ring, 1 gll16/thread/tile, 2 tiles in flight, vmcnt(1).
// LDS 51200 B -> 3 blocks/CU: grid 2304 = EXACTLY 3 residency rounds (was 4.5 at
// 2/CU -> ~11% tail waste), k_proj 768 = exactly 1 round; 3 barrier groups drift.
// Ring-3 hazards: at barrier for tile t, write slot (t+2)%3 == (t-1)%3 (reads done
// before previous barrier); read t%3; live (t+1)%3 -- distinct. Depth-2 prefetch
// covers W latency (~1250 cy/tile >> 900 cy HBM; W is L2-hot anyway).
// ======================================================================================
#define XLDS_U16 13312                 // 26624 B X region (64 rows x 416 B)
#define WSLOT_U16 4096                 // 8 KB per W buffer slot

#define GISSUE(kt) gll16(Wp + (kt) * 32, &lds[XLDS_U16 + ((kt) % 3) * WSLOT_U16 + wst])

#define SYNCP(n) do { \
    asm volatile("s_waitcnt vmcnt(" #n ")" ::: "memory"); \
    __builtin_amdgcn_s_barrier(); \
    asm volatile("" ::: "memory"); \
  } while (0)

#define COMPUTE(kt) do { \
    const u8* xb_ = (const u8*)lds; \
    const u16* wb_ = &lds[XLDS_U16 + ((kt) % 3) * WSLOT_U16]; \
    bf16x8 ax[2]; \
    _Pragma("unroll") \
    for (int ji = 0; ji < 2; ++ji) { \
      uint2 xr_ = *(const uint2*)(xb_ + (w * 8 + ji * 4 + d4) * 416 + (kt) * 32 + g8); \
      uint4 e_ = expand8f(xr_, t_lane); \
      ax[ji] = *(bf16x8*)&e_; \
    } \
    __builtin_amdgcn_s_setprio(1); \
    _Pragma("unroll") \
    for (int ci = 0; ci < 8; ++ci) { \
      bf16x8 bw_ = *(const bf16x8*)&wb_[(ci * 16 + l15) * 32 + swoff]; \
      _Pragma("unroll") \
      for (int ji = 0; ji < 2; ++ji) \
        acc[ji][ci] = __builtin_amdgcn_mfma_f32_16x16x32_bf16(ax[ji], bw_, acc[ji][ci], 0, 0, 0); \
    } \
    __builtin_amdgcn_s_setprio(0); \
  } while (0)

#define GEMM_PIPELINE() do { \
    GISSUE(0); GISSUE(1); \
    SYNCP(1); GISSUE(2);  COMPUTE(0); \
    SYNCP(1); GISSUE(3);  COMPUTE(1); \
    SYNCP(1); GISSUE(4);  COMPUTE(2); \
    SYNCP(1); GISSUE(5);  COMPUTE(3); \
    SYNCP(1); GISSUE(6);  COMPUTE(4); \
    SYNCP(1); GISSUE(7);  COMPUTE(5); \
    SYNCP(1); GISSUE(8);  COMPUTE(6); \
    SYNCP(1); GISSUE(9);  COMPUTE(7); \
    SYNCP(1); GISSUE(10); COMPUTE(8); \
    SYNCP(1); GISSUE(11); COMPUTE(9); \
    SYNCP(1); COMPUTE(10); \
    SYNCP(0); COMPUTE(11); \
  } while (0)

// stage packed X strip (64 n x 384 B) into padded LDS rows (416 B), then sync
#define XSTAGE(XSRC) do { \
    const int xn_ = tid >> 3, xcp_ = tid & 7; \
    const u8* xs_ = (XSRC) + (size_t)(b * 1024 + jt * 64 + xn_) * 384 + xcp_ * 48; \
    u8* xd_ = (u8*)lds + xn_ * 416 + xcp_ * 48; \
    uint4 v0_ = *(const uint4*)(xs_); \
    uint4 v1_ = *(const uint4*)(xs_ + 16); \
    uint4 v2_ = *(const uint4*)(xs_ + 32); \
    *(uint4*)(xd_) = v0_; *(uint4*)(xd_ + 16) = v1_; *(uint4*)(xd_ + 32) = v2_; \
    __syncthreads(); \
  } while (0)

#define GEMM_SETUP() \
  const int tid = threadIdx.x; \
  const int w = tid >> 6, l = tid & 63; \
  const int l15 = tid & 15, g = l >> 4; \
  const int swoff = (g ^ ((l15 >> 1) & 3)) * 8; \
  const int wst = w * 512; \
  const int d4 = l15 >> 2, g8 = g * 8; \
  const u32 t_lane = (u32)(l15 & 3); \
  const int sch = (l & 3) ^ ((l >> 3) & 3); \
  f32x4 acc[2][8]; \
  { const f32x4 zero_ = {0.f, 0.f, 0.f, 0.f}; \
    _Pragma("unroll") \
    for (int ji = 0; ji < 2; ++ji) \
      _Pragma("unroll") \
      for (int ci = 0; ci < 8; ++ci) acc[ji][ci] = zero_; }

// ---------------- K2: qkv GEMM (one branch-panel per block) + BN + LIF -> sp nibbles --
__global__ __launch_bounds__(512, 6) void k_qkv(
    const u16* __restrict__ Wstk, const u8* __restrict__ xsb,
    const float4* __restrict__ BNP, u8* __restrict__ sp) {
  const int jt = blockIdx.x, mt = blockIdx.y, b = blockIdx.z;
  __shared__ u16 lds[25600];                      // 26624B X + 3x8KB W = 51200 B

  GEMM_SETUP();
  XSTAGE(xsb);

  const int m0 = mt * 128;                        // == (mt/3)*384 + (mt%3)*128 in Wstk
  const u16* Wp = Wstk + (size_t)(m0 + w * 16 + (l >> 2)) * 384 + sch * 8;

  GEMM_PIPELINE();

  // epilogue: BN + 4-step LIF (acc regs = t), pack 4 spike bits -> one u8
  const int br = mt / 3;
  const int cb = (mt - br * 3) * 128;
  const int n_base = b * 1024 + jt * 64 + w * 8 + g;
  u8* spW = sp + (size_t)br * SPB;
  #pragma unroll
  for (int ci = 0; ci < 8; ++ci) {
    const int c_loc = ci * 16 + l15;
    float4 pr = BNP[br * 384 + cb + c_loc];       // direct L2 load
    #pragma unroll
    for (int ji = 0; ji < 2; ++ji) {
      f32x4 a = acc[ji][ci];
      u32 bits = 0;
      float vv = 0.f;
      #pragma unroll
      for (int t = 0; t < 4; ++t) {
        float z = __fadd_rn(__fmul_rn(__fsub_rn(a[t], pr.y), pr.x), pr.z);  // BN, ref order
        float h = __fadd_rn(vv, __fmul_rn(__fsub_rn(z, vv), 0.5f));          // LIF step
        bool s = h >= 1.f;
        vv = s ? 0.f : h;
        bits |= (s ? 1u : 0u) << t;
      }
      spW[(size_t)(n_base + ji * 4) * 384 + cb + c_loc] = (u8)bits;
    }
  }
}

// ---------------- K4: P GEMM + FUSED attn (k&v head-sum, LIF(0.5), q-mask) ------------
// Stage thread-map (row=tid>>3, chunk=tid&7): one 48-B chunk == one head, so the attn
// reduction + LIF scan + q-mask are fully thread-local (integer fp32 -> bit-exact).
__global__ __launch_bounds__(512, 6) void k_proj(
    const u16* __restrict__ Pw, const u8* __restrict__ sp,
    const float4* __restrict__ PP, float* __restrict__ out) {
  const int jt = blockIdx.x, mt = blockIdx.y, b = blockIdx.z;
  __shared__ u16 lds[25600];

  {                                                // fused attn + X stage
    const int tt = threadIdx.x;
    const int xn_ = tt >> 3, hd_ = tt & 7;
    const u8* qrow = sp + (size_t)(b * 1024 + jt * 64 + xn_) * 384 + hd_ * 48;
    const u8* krow = qrow + SPB;
    const u8* vrow = qrow + 2 * SPB;
    u32 qa[12], ka[12], va[12];
    #pragma unroll
    for (int i = 0; i < 3; ++i) {
      *(uint4*)&qa[i * 4] = *(const uint4*)(qrow + i * 16);
      *(uint4*)&ka[i * 4] = *(const uint4*)(krow + i * 16);
      *(uint4*)&va[i * 4] = *(const uint4*)(vrow + i * 16);
    }
    u32 m0 = 0, m1 = 0, m2 = 0, m3 = 0;
    #pragma unroll
    for (int i = 0; i < 12; ++i) {
      u32 a = ka[i] & va[i];
      m0 += a & 0x01010101u;
      m1 += (a >> 1) & 0x01010101u;
      m2 += (a >> 2) & 0x01010101u;
      m3 += (a >> 3) & 0x01010101u;
    }
    float s0 = (float)((m0 * 0x01010101u) >> 24);  // head sums per t, <= 48, exact
    float s1 = (float)((m1 * 0x01010101u) >> 24);
    float s2 = (float)((m2 * 0x01010101u) >> 24);
    float s3 = (float)((m3 * 0x01010101u) >> 24);
    float vv = 0.f;
    u32 m8 = 0;
    #pragma unroll
    for (int t = 0; t < 4; ++t) {
      float attn = (t == 0) ? s0 : (t == 1) ? s1 : (t == 2) ? s2 : s3;
      float h = __fadd_rn(vv, __fmul_rn(__fsub_rn(attn, vv), 0.5f));
      bool sk = h >= 0.5f;
      vv = sk ? 0.f : h;
      m8 |= (sk ? 1u : 0u) << t;
    }
    const u32 mm = m8 * 0x01010101u;
    u8* xd_ = (u8*)lds + xn_ * 416 + hd_ * 48;
    #pragma unroll
    for (int i = 0; i < 3; ++i) {
      uint4 wv;
      wv.x = qa[i * 4 + 0] & mm;
      wv.y = qa[i * 4 + 1] & mm;
      wv.z = qa[i * 4 + 2] & mm;
      wv.w = qa[i * 4 + 3] & mm;
      *(uint4*)(xd_ + i * 16) = wv;
    }
    __syncthreads();
  }

  GEMM_SETUP();

  const int m0 = mt * 128;
  const u16* Wp = Pw + (size_t)(m0 + w * 16 + (l >> 2)) * 384 + sch * 8;

  GEMM_PIPELINE();

  __syncthreads();                                 // all waves done with LDS buffers
  float* scr = (float*)lds;                        // 128 x 68-padded f32 tile (34.8 KB)
  const int n0im = jt * 64;
  float4 prc[8];
  #pragma unroll
  for (int ci = 0; ci < 8; ++ci) prc[ci] = PP[m0 + ci * 16 + l15];

  #pragma unroll
  for (int t = 0; t < 4; ++t) {
    #pragma unroll
    for (int ci = 0; ci < 8; ++ci) {
      const int c_loc = ci * 16 + l15;
      float4 pr = prc[ci];
      #pragma unroll
      for (int ji = 0; ji < 2; ++ji) {
        const int n_loc = w * 8 + ji * 4 + g;
        float zz = __fadd_rn(acc[ji][ci][t], pr.w);                        // + bias
        zz = __fadd_rn(__fmul_rn(__fsub_rn(zz, pr.y), pr.x), pr.z);        // BN, ref order
        scr[c_loc * 68 + n_loc] = zz;
      }
    }
    __syncthreads();
    #pragma unroll
    for (int it = 0; it < 4; ++it) {
      int slot = tid + it * 512;                   // 2048 slots = 128 rows x 16 float4
      int c = slot >> 4, li = slot & 15;
      float4 val = *(const float4*)&scr[c * 68 + li * 4];
      *(float4*)&out[(((size_t)(t * 16 + b) * 384) + m0 + c) * 1024 + n0im + li * 4] = val;
    }
    __syncthreads();
  }
}

extern "C" void kernel_launch(void* const* d_in, const int* in_sizes, int n_in,
                              void* d_out, int out_size, void* d_ws, size_t ws_size,
                              hipStream_t stream) {
  (void)in_sizes; (void)n_in; (void)out_size; (void)ws_size;
  const float* x   = (const float*)d_in[0];
  const float* qw  = (const float*)d_in[1];
  const float* qg  = (const float*)d_in[2];
  const float* qbt = (const float*)d_in[3];
  const float* qm  = (const float*)d_in[4];
  const float* qv  = (const float*)d_in[5];
  const float* kw  = (const float*)d_in[6];
  const float* kg  = (const float*)d_in[7];
  const float* kbt = (const float*)d_in[8];
  const float* km  = (const float*)d_in[9];
  const float* kv  = (const float*)d_in[10];
  const float* vw  = (const float*)d_in[11];
  const float* vg  = (const float*)d_in[12];
  const float* vbt = (const float*)d_in[13];
  const float* vm  = (const float*)d_in[14];
  const float* vv  = (const float*)d_in[15];
  const float* pw  = (const float*)d_in[16];
  const float* pg  = (const float*)d_in[17];
  const float* pbt = (const float*)d_in[18];
  const float* pm  = (const float*)d_in[19];
  const float* pv  = (const float*)d_in[20];
  const float* pbias = (const float*)d_in[21];

  char* ws = (char*)d_ws;
  u8*  xsb   = (u8*)ws;                     // input spikes, packed nibbles (6.3 MB)
  u8*  sp    = (u8*)(ws + 6291456);         // q,k,v spike nibbles (3 x 6.3 MB)
  u16* Wstk  = (u16*)(ws + 31457280);       // [1152][384] bf16
  u16* Pw    = (u16*)(ws + 32342016);       // [384][384] bf16
  float4* BNP = (float4*)(ws + 32636928);   // [1152]
  float4* PP  = (float4*)(ws + 32655360);   // [384]

  k_convert<<<2310, 256, 0, stream>>>(qw, kw, vw, pw, qg, qbt, qm, qv, kg, kbt, km, kv,
                                      vg, vbt, vm, vv, pg, pbt, pm, pv, pbias,
                                      Wstk, Pw, BNP, PP);
  k_lif_in<<<dim3(16, 6, 16), 256, 0, stream>>>(x, xsb);
  k_qkv<<<dim3(16, 9, 16), 512, 0, stream>>>(Wstk, xsb, BNP, sp);
  k_proj<<<dim3(16, 3, 16), 512, 0, stream>>>(Pw, sp, PP, (float*)d_out);
}

// Round 16
// 113.294 us; speedup vs baseline: 2.4514x; 2.4514x over previous
//
#include <hip/hip_runtime.h>

typedef unsigned short u16;
typedef unsigned char u8;
typedef unsigned int u32;
typedef float f32x4 __attribute__((ext_vector_type(4)));
typedef __bf16 bf16x8 __attribute__((ext_vector_type(8)));

#define SPB 6291456      // bytes per packed branch: B*N*C = 16*1024*384 (u8, 4 t-bits)

// ---- async global->LDS, 16B per lane, dest = wave-uniform base + lane*16 ----
__device__ __forceinline__ void gll16(const void* g, void* l) {
  __builtin_amdgcn_global_load_lds((const __attribute__((address_space(1))) void*)g,
                                   (__attribute__((address_space(3))) void*)l, 16, 0, 0);
}

// expand 8 packed spike-bytes (bit t) -> 8 bf16 {0,1}; perm+mul: (b0|b1<<16)*0x3F80
__device__ __forceinline__ uint4 expand8f(uint2 v, u32 t) {
  u32 a = (v.x >> t) & 0x01010101u;
  u32 b = (v.y >> t) & 0x01010101u;
  uint4 r;
  r.x = __builtin_amdgcn_perm(0u, a, 0x0C010C00u) * 0x3F80u;
  r.y = __builtin_amdgcn_perm(0u, a, 0x0C030C02u) * 0x3F80u;
  r.z = __builtin_amdgcn_perm(0u, b, 0x0C010C00u) * 0x3F80u;
  r.w = __builtin_amdgcn_perm(0u, b, 0x0C030C02u) * 0x3F80u;
  return r;
}

// ---------------- K0: weights -> bf16 (stacked q,k,v), BN params fused ----------------
__global__ __launch_bounds__(256) void k_convert(
    const float* __restrict__ qw, const float* __restrict__ kw,
    const float* __restrict__ vw, const float* __restrict__ pw,
    const float* __restrict__ qg, const float* __restrict__ qbt,
    const float* __restrict__ qm, const float* __restrict__ qv,
    const float* __restrict__ kg, const float* __restrict__ kbt,
    const float* __restrict__ km, const float* __restrict__ kv,
    const float* __restrict__ vg, const float* __restrict__ vbt,
    const float* __restrict__ vm, const float* __restrict__ vv,
    const float* __restrict__ pg, const float* __restrict__ pbt,
    const float* __restrict__ pm, const float* __restrict__ pv,
    const float* __restrict__ pbias,
    u16* __restrict__ Wstk, u16* __restrict__ Pw,
    float4* __restrict__ BNP, float4* __restrict__ PP) {
  int tid = blockIdx.x * 256 + threadIdx.x;
  if (tid < 442368) {               // Wstk[1152][384]
    int r = tid / 384, c = tid - r * 384;
    const float* src = (r < 384) ? qw : (r < 768) ? kw : vw;
    int rr = (r >= 768) ? r - 768 : (r >= 384) ? r - 384 : r;
    unsigned int u = __float_as_uint(src[rr * 384 + c]);
    u = (u + 0x7FFFu + ((u >> 16) & 1u)) >> 16;   // RNE to bf16
    Wstk[tid] = (u16)u;
  } else if (tid < 589824) {        // Pw[384][384]
    int i = tid - 442368;
    unsigned int u = __float_as_uint(pw[i]);
    u = (u + 0x7FFFu + ((u >> 16) & 1u)) >> 16;
    Pw[i] = (u16)u;
  } else if (tid < 590976) {        // BNP[1152] = {inv, mean, beta, -}
    int r = tid - 589824;
    int br = r / 384, ch = r - br * 384;
    const float* g  = (br == 0) ? qg  : (br == 1) ? kg  : vg;
    const float* bt = (br == 0) ? qbt : (br == 1) ? kbt : vbt;
    const float* m  = (br == 0) ? qm  : (br == 1) ? km  : vm;
    const float* va = (br == 0) ? qv  : (br == 1) ? kv  : vv;
    float inv = g[ch] / sqrtf(va[ch] + 1e-5f);
    BNP[r] = make_float4(inv, m[ch], bt[ch], 0.f);
  } else if (tid < 591360) {        // PP[384] = {inv, mean, beta, bias}
    int ch = tid - 590976;
    float inv = pg[ch] / sqrtf(pv[ch] + 1e-5f);
    PP[ch] = make_float4(inv, pm[ch], pbt[ch], pbias[ch]);
  }
}

// ---------------- K1: input LIF -> packed nibble xsb[(b*1024+n)*384 + c] --------------
// float4 reads along n (4x fewer load instrs than scalar); phase-2 transpose unchanged.
__global__ __launch_bounds__(256) void k_lif_in(const float* __restrict__ x, u8* __restrict__ xsb) {
  const int nt = blockIdx.x, ct = blockIdx.y, b = blockIdx.z;
  const int tid = threadIdx.x;
  const int n4 = tid & 15, cL = tid >> 4;     // 16 n-quads x 16 c-lanes
  const int c0 = ct * 64, n0 = nt * 64;
  __shared__ u32 nibs[64 * 65];               // [n][c], 65-pad -> 2-way max on writes
  float v[4][4];
  u32 nib[4][4];
  #pragma unroll
  for (int it = 0; it < 4; ++it)
    #pragma unroll
    for (int ns = 0; ns < 4; ++ns) { v[it][ns] = 0.f; nib[it][ns] = 0u; }
  for (int t = 0; t < 4; ++t) {
    #pragma unroll
    for (int it = 0; it < 4; ++it) {
      const float4 xv = *(const float4*)&x[(size_t)(((t * 16 + b) * 384 + c0 + cL + it * 16)) * 1024
                                           + n0 + n4 * 4];
      #pragma unroll
      for (int ns = 0; ns < 4; ++ns) {
        float xe = (ns == 0) ? xv.x : (ns == 1) ? xv.y : (ns == 2) ? xv.z : xv.w;
        float vv = v[it][ns];
        float h = __fadd_rn(vv, __fmul_rn(__fsub_rn(xe, vv), 0.5f));  // v + (x-v)/2, exact order
        bool s = h >= 1.f;
        v[it][ns] = s ? 0.f : h;
        nib[it][ns] |= (s ? 1u : 0u) << t;
      }
    }
  }
  #pragma unroll
  for (int it = 0; it < 4; ++it)
    #pragma unroll
    for (int ns = 0; ns < 4; ++ns)
      nibs[(n4 * 4 + ns) * 65 + cL + it * 16] = nib[it][ns];
  __syncthreads();
  const int n = tid >> 2, ch = tid & 3;
  u32 w0[4];
  #pragma unroll
  for (int q = 0; q < 4; ++q) {
    u32 acc = 0;
    #pragma unroll
    for (int i = 0; i < 4; ++i)
      acc |= (nibs[n * 65 + ch * 16 + q * 4 + i] & 0xFu) << (8 * i);
    w0[q] = acc;
  }
  *(uint4*)(xsb + ((size_t)(b * 1024 + n0 + n)) * 384 + c0 + ch * 16) =
      make_uint4(w0[0], w0[1], w0[2], w0[3]);
}

// ======================================================================================
// GEMM core v9 (R14, best measured): BM=128 c, BN=256 j (64 n x 4 t), K=384, 8 waves.
// Wave w owns 8 n-rows (32 j) and ALL 128 c: ji=2, ci=8 -> 16 MFMA/wave/tile, unique-A.
// X packed-resident in LDS (26 KB, 416B-padded rows), expanded to bf16 on read.
// W pipelined: 6 x 8KB ring, 1 gll16/thread/tile, 4 tiles in flight, vmcnt(2),
// TWO K-tiles per barrier interval. LDS 75776 B -> 2 blocks/CU, 4 waves/SIMD.
// NOTE (R15 lesson): 3 blocks/CU is unreachable — 124 regs/wave (60 VGPR + 64 acc)
// caps HW at 4 waves/SIMD; forcing launch_bounds(512,6) spills acc (-2.4x perf).
// ======================================================================================
#define XLDS_U16 13312                 // 26624 B X region (64 rows x 416 B)
#define WSLOT_U16 4096                 // 8 KB per W buffer slot

#define GISSUE(kt) gll16(Wp + (kt) * 32, &lds[XLDS_U16 + ((kt) % 6) * WSLOT_U16 + wst])

#define SYNCP(n) do { \
    asm volatile("s_waitcnt vmcnt(" #n ")" ::: "memory"); \
    __builtin_amdgcn_s_barrier(); \
    asm volatile("" ::: "memory"); \
  } while (0)

#define COMPUTE(kt) do { \
    const u8* xb_ = (const u8*)lds; \
    const u16* wb_ = &lds[XLDS_U16 + ((kt) % 6) * WSLOT_U16]; \
    bf16x8 ax[2]; \
    _Pragma("unroll") \
    for (int ji = 0; ji < 2; ++ji) { \
      uint2 xr_ = *(const uint2*)(xb_ + (w * 8 + ji * 4 + d4) * 416 + (kt) * 32 + g8); \
      uint4 e_ = expand8f(xr_, t_lane); \
      ax[ji] = *(bf16x8*)&e_; \
    } \
    __builtin_amdgcn_s_setprio(1); \
    _Pragma("unroll") \
    for (int ci = 0; ci < 8; ++ci) { \
      bf16x8 bw_ = *(const bf16x8*)&wb_[(ci * 16 + l15) * 32 + swoff]; \
      _Pragma("unroll") \
      for (int ji = 0; ji < 2; ++ji) \
        acc[ji][ci] = __builtin_amdgcn_mfma_f32_16x16x32_bf16(ax[ji], bw_, acc[ji][ci], 0, 0, 0); \
    } \
    __builtin_amdgcn_s_setprio(0); \
  } while (0)

#define GEMM_PIPELINE() do { \
    GISSUE(0); GISSUE(1); GISSUE(2); GISSUE(3); \
    SYNCP(2); GISSUE(4);  GISSUE(5);  COMPUTE(0);  COMPUTE(1); \
    SYNCP(2); GISSUE(6);  GISSUE(7);  COMPUTE(2);  COMPUTE(3); \
    SYNCP(2); GISSUE(8);  GISSUE(9);  COMPUTE(4);  COMPUTE(5); \
    SYNCP(2); GISSUE(10); GISSUE(11); COMPUTE(6);  COMPUTE(7); \
    SYNCP(2); COMPUTE(8);  COMPUTE(9); \
    SYNCP(0); COMPUTE(10); COMPUTE(11); \
  } while (0)

// stage packed X strip (64 n x 384 B) into padded LDS rows (416 B), then sync
#define XSTAGE(XSRC) do { \
    const int xn_ = tid >> 3, xcp_ = tid & 7; \
    const u8* xs_ = (XSRC) + (size_t)(b * 1024 + jt * 64 + xn_) * 384 + xcp_ * 48; \
    u8* xd_ = (u8*)lds + xn_ * 416 + xcp_ * 48; \
    uint4 v0_ = *(const uint4*)(xs_); \
    uint4 v1_ = *(const uint4*)(xs_ + 16); \
    uint4 v2_ = *(const uint4*)(xs_ + 32); \
    *(uint4*)(xd_) = v0_; *(uint4*)(xd_ + 16) = v1_; *(uint4*)(xd_ + 32) = v2_; \
    __syncthreads(); \
  } while (0)

#define GEMM_SETUP() \
  const int tid = threadIdx.x; \
  const int w = tid >> 6, l = tid & 63; \
  const int l15 = tid & 15, g = l >> 4; \
  const int swoff = (g ^ ((l15 >> 1) & 3)) * 8; \
  const int wst = w * 512; \
  const int d4 = l15 >> 2, g8 = g * 8; \
  const u32 t_lane = (u32)(l15 & 3); \
  const int sch = (l & 3) ^ ((l >> 3) & 3); \
  f32x4 acc[2][8]; \
  { const f32x4 zero_ = {0.f, 0.f, 0.f, 0.f}; \
    _Pragma("unroll") \
    for (int ji = 0; ji < 2; ++ji) \
      _Pragma("unroll") \
      for (int ci = 0; ci < 8; ++ci) acc[ji][ci] = zero_; }

// ---------------- K2: qkv GEMM (one branch-panel per block) + BN + LIF -> sp nibbles --
__global__ __launch_bounds__(512, 4) void k_qkv(
    const u16* __restrict__ Wstk, const u8* __restrict__ xsb,
    const float4* __restrict__ BNP, u8* __restrict__ sp) {
  const int jt = blockIdx.x, mt = blockIdx.y, b = blockIdx.z;
  __shared__ u16 lds[37888];                      // 26624B X + 6x8KB W = 75776 B

  GEMM_SETUP();
  XSTAGE(xsb);

  const int m0 = mt * 128;                        // == (mt/3)*384 + (mt%3)*128 in Wstk
  const u16* Wp = Wstk + (size_t)(m0 + w * 16 + (l >> 2)) * 384 + sch * 8;

  GEMM_PIPELINE();

  // epilogue: BN + 4-step LIF (acc regs = t), pack 4 spike bits -> one u8
  const int br = mt / 3;
  const int cb = (mt - br * 3) * 128;
  const int n_base = b * 1024 + jt * 64 + w * 8 + g;
  u8* spW = sp + (size_t)br * SPB;
  #pragma unroll
  for (int ci = 0; ci < 8; ++ci) {
    const int c_loc = ci * 16 + l15;
    float4 pr = BNP[br * 384 + cb + c_loc];       // direct L2 load
    #pragma unroll
    for (int ji = 0; ji < 2; ++ji) {
      f32x4 a = acc[ji][ci];
      u32 bits = 0;
      float vv = 0.f;
      #pragma unroll
      for (int t = 0; t < 4; ++t) {
        float z = __fadd_rn(__fmul_rn(__fsub_rn(a[t], pr.y), pr.x), pr.z);  // BN, ref order
        float h = __fadd_rn(vv, __fmul_rn(__fsub_rn(z, vv), 0.5f));          // LIF step
        bool s = h >= 1.f;
        vv = s ? 0.f : h;
        bits |= (s ? 1u : 0u) << t;
      }
      spW[(size_t)(n_base + ji * 4) * 384 + cb + c_loc] = (u8)bits;
    }
  }
}

// ---------------- K4: P GEMM + FUSED attn (k&v head-sum, LIF(0.5), q-mask) ------------
// Stage thread-map (row=tid>>3, chunk=tid&7): one 48-B chunk == one head, so the attn
// reduction + LIF scan + q-mask are fully thread-local (integer fp32 -> bit-exact).
__global__ __launch_bounds__(512, 4) void k_proj(
    const u16* __restrict__ Pw, const u8* __restrict__ sp,
    const float4* __restrict__ PP, float* __restrict__ out) {
  const int jt = blockIdx.x, mt = blockIdx.y, b = blockIdx.z;
  __shared__ u16 lds[37888];

  {                                                // fused attn + X stage
    const int tt = threadIdx.x;
    const int xn_ = tt >> 3, hd_ = tt & 7;
    const u8* qrow = sp + (size_t)(b * 1024 + jt * 64 + xn_) * 384 + hd_ * 48;
    const u8* krow = qrow + SPB;
    const u8* vrow = qrow + 2 * SPB;
    u32 qa[12], ka[12], va[12];
    #pragma unroll
    for (int i = 0; i < 3; ++i) {
      *(uint4*)&qa[i * 4] = *(const uint4*)(qrow + i * 16);
      *(uint4*)&ka[i * 4] = *(const uint4*)(krow + i * 16);
      *(uint4*)&va[i * 4] = *(const uint4*)(vrow + i * 16);
    }
    u32 m0 = 0, m1 = 0, m2 = 0, m3 = 0;
    #pragma unroll
    for (int i = 0; i < 12; ++i) {
      u32 a = ka[i] & va[i];
      m0 += a & 0x01010101u;
      m1 += (a >> 1) & 0x01010101u;
      m2 += (a >> 2) & 0x01010101u;
      m3 += (a >> 3) & 0x01010101u;
    }
    float s0 = (float)((m0 * 0x01010101u) >> 24);  // head sums per t, <= 48, exact
    float s1 = (float)((m1 * 0x01010101u) >> 24);
    float s2 = (float)((m2 * 0x01010101u) >> 24);
    float s3 = (float)((m3 * 0x01010101u) >> 24);
    float vv = 0.f;
    u32 m8 = 0;
    #pragma unroll
    for (int t = 0; t < 4; ++t) {
      float attn = (t == 0) ? s0 : (t == 1) ? s1 : (t == 2) ? s2 : s3;
      float h = __fadd_rn(vv, __fmul_rn(__fsub_rn(attn, vv), 0.5f));
      bool sk = h >= 0.5f;
      vv = sk ? 0.f : h;
      m8 |= (sk ? 1u : 0u) << t;
    }
    const u32 mm = m8 * 0x01010101u;
    u8* xd_ = (u8*)lds + xn_ * 416 + hd_ * 48;
    #pragma unroll
    for (int i = 0; i < 3; ++i) {
      uint4 wv;
      wv.x = qa[i * 4 + 0] & mm;
      wv.y = qa[i * 4 + 1] & mm;
      wv.z = qa[i * 4 + 2] & mm;
      wv.w = qa[i * 4 + 3] & mm;
      *(uint4*)(xd_ + i * 16) = wv;
    }
    __syncthreads();
  }

  GEMM_SETUP();

  const int m0 = mt * 128;
  const u16* Wp = Pw + (size_t)(m0 + w * 16 + (l >> 2)) * 384 + sch * 8;

  GEMM_PIPELINE();

  __syncthreads();                                 // all waves done with LDS buffers
  float* scr = (float*)lds;                        // 128 x 68-padded f32 tile (34.8 KB)
  const int n0im = jt * 64;
  float4 prc[8];
  #pragma unroll
  for (int ci = 0; ci < 8; ++ci) prc[ci] = PP[m0 + ci * 16 + l15];

  #pragma unroll
  for (int t = 0; t < 4; ++t) {
    #pragma unroll
    for (int ci = 0; ci < 8; ++ci) {
      const int c_loc = ci * 16 + l15;
      float4 pr = prc[ci];
      #pragma unroll
      for (int ji = 0; ji < 2; ++ji) {
        const int n_loc = w * 8 + ji * 4 + g;
        float zz = __fadd_rn(acc[ji][ci][t], pr.w);                        // + bias
        zz = __fadd_rn(__fmul_rn(__fsub_rn(zz, pr.y), pr.x), pr.z);        // BN, ref order
        scr[c_loc * 68 + n_loc] = zz;
      }
    }
    __syncthreads();
    #pragma unroll
    for (int it = 0; it < 4; ++it) {
      int slot = tid + it * 512;                   // 2048 slots = 128 rows x 16 float4
      int c = slot >> 4, li = slot & 15;
      float4 val = *(const float4*)&scr[c * 68 + li * 4];
      *(float4*)&out[(((size_t)(t * 16 + b) * 384) + m0 + c) * 1024 + n0im + li * 4] = val;
    }
    __syncthreads();
  }
}

extern "C" void kernel_launch(void* const* d_in, const int* in_sizes, int n_in,
                              void* d_out, int out_size, void* d_ws, size_t ws_size,
                              hipStream_t stream) {
  (void)in_sizes; (void)n_in; (void)out_size; (void)ws_size;
  const float* x   = (const float*)d_in[0];
  const float* qw  = (const float*)d_in[1];
  const float* qg  = (const float*)d_in[2];
  const float* qbt = (const float*)d_in[3];
  const float* qm  = (const float*)d_in[4];
  const float* qv  = (const float*)d_in[5];
  const float* kw  = (const float*)d_in[6];
  const float* kg  = (const float*)d_in[7];
  const float* kbt = (const float*)d_in[8];
  const float* km  = (const float*)d_in[9];
  const float* kv  = (const float*)d_in[10];
  const float* vw  = (const float*)d_in[11];
  const float* vg  = (const float*)d_in[12];
  const float* vbt = (const float*)d_in[13];
  const float* vm  = (const float*)d_in[14];
  const float* vv  = (const float*)d_in[15];
  const float* pw  = (const float*)d_in[16];
  const float* pg  = (const float*)d_in[17];
  const float* pbt = (const float*)d_in[18];
  const float* pm  = (const float*)d_in[19];
  const float* pv  = (const float*)d_in[20];
  const float* pbias = (const float*)d_in[21];

  char* ws = (char*)d_ws;
  u8*  xsb   = (u8*)ws;                     // input spikes, packed nibbles (6.3 MB)
  u8*  sp    = (u8*)(ws + 6291456);         // q,k,v spike nibbles (3 x 6.3 MB)
  u16* Wstk  = (u16*)(ws + 31457280);       // [1152][384] bf16
  u16* Pw    = (u16*)(ws + 32342016);       // [384][384] bf16
  float4* BNP = (float4*)(ws + 32636928);   // [1152]
  float4* PP  = (float4*)(ws + 32655360);   // [384]

  k_convert<<<2310, 256, 0, stream>>>(qw, kw, vw, pw, qg, qbt, qm, qv, kg, kbt, km, kv,
                                      vg, vbt, vm, vv, pg, pbt, pm, pv, pbias,
                                      Wstk, Pw, BNP, PP);
  k_lif_in<<<dim3(16, 6, 16), 256, 0, stream>>>(x, xsb);
  k_qkv<<<dim3(16, 9, 16), 512, 0, stream>>>(Wstk, xsb, BNP, sp);
  k_proj<<<dim3(16, 3, 16), 512, 0, stream>>>(Pw, sp, PP, (float*)d_out);
}